// Round 9
// baseline (53.268 us; speedup 1.0000x reference)
//
#include <hip/hip_runtime.h>
#include <hip/hip_cooperative_groups.h>

namespace cg = cooperative_groups;

#define PN 2048

typedef __attribute__((ext_vector_type(8))) short short8;
typedef __attribute__((ext_vector_type(4))) float f32x4;

static __device__ __forceinline__ unsigned int pk_bf2(float lo, float hi) {
    unsigned int ul = __float_as_uint(lo);
    unsigned int uh = __float_as_uint(hi);
    ul = (ul + 0x7fffu + ((ul >> 16) & 1u)) >> 16;   // RNE f32->bf16
    uh = (uh + 0x7fffu + ((uh >> 16) & 1u)) >> 16;
    return ul | (uh << 16);
}

// Single GEMM: M[p,k] = dot(X[2p], X[2k+1])/128, T = exp(1+M).
// neg[p] = rowsum_p(T)[excl k==2p+1] + colsum_p(T)[excl row==2p];
// J[p] = log(1e-8+neg[p]) - M[p,p]; out = mean(max(J,0)^2).
// One cooperative kernel: GEMM phase -> grid.sync -> distributed finish.
// ws: Srow[16][2048], Scol[16][2048], Dpos[2048] (all written before sync, read after).
// Tile 128x128, grid (16,16)=256 blocks (1/CU), 512 thr (8 waves).

__global__ __launch_bounds__(512, 1) void sml_coop(
    const float* __restrict__ X, float* __restrict__ Srow, float* __restrict__ Scol,
    float* __restrict__ Dpos, float* __restrict__ out)
{
    __shared__ __align__(16) unsigned int A_s[128 * 32];  // bf16[128][64], 16B-slot XOR-swizzled
    __shared__ __align__(16) unsigned int B_s[128 * 32];
    __shared__ float red[4][128];

    const int bx = blockIdx.x, by = blockIdx.y;
    const int t = threadIdx.x;                 // 0..511, 8 waves
    const int lane = t & 63, wid = t >> 6;
    const int wr = wid >> 2, wc = wid & 3;     // wave grid 2x4 over (64-row x 32-col) subtiles
    const int g4 = lane >> 4, rl = lane & 15;

    if (bx == 0 && by == 0 && t == 0) out[0] = 0.f;   // finish phase accumulates atomically

    // staging: thread handles 16B k-slot s of rows r0 + 64q (q=0,1), A (even rows) B (odd rows)
    const int s  = t & 7;
    const int r0 = t >> 3;

    const float* aptr[2];
    const float* bptr[2];
    #pragma unroll
    for (int q = 0; q < 2; ++q) {
        const int r = r0 + 64 * q;
        aptr[q] = X + (size_t)(2 * (bx * 128 + r)) * 256 + s * 8;
        bptr[q] = X + (size_t)(2 * (by * 128 + r) + 1) * 256 + s * 8;
    }

    f32x4 acc[4][2];
    #pragma unroll
    for (int i = 0; i < 4; ++i)
        #pragma unroll
        for (int j = 0; j < 2; ++j) acc[i][j] = (f32x4){0.f, 0.f, 0.f, 0.f};

    float4 pa[2][2], pb[2][2];
    #pragma unroll
    for (int q = 0; q < 2; ++q) {
        pa[q][0] = *(const float4*)(aptr[q]);
        pa[q][1] = *(const float4*)(aptr[q] + 4);
        pb[q][0] = *(const float4*)(bptr[q]);
        pb[q][1] = *(const float4*)(bptr[q] + 4);
    }

    for (int ks = 0; ks < 4; ++ks) {
        __syncthreads();   // previous chunk's LDS reads done
        #pragma unroll
        for (int q = 0; q < 2; ++q) {
            const int r  = r0 + 64 * q;
            const int sw = (s ^ (r & 7)) << 2;
            uint4 wa = { pk_bf2(pa[q][0].x, pa[q][0].y), pk_bf2(pa[q][0].z, pa[q][0].w),
                         pk_bf2(pa[q][1].x, pa[q][1].y), pk_bf2(pa[q][1].z, pa[q][1].w) };
            uint4 wb = { pk_bf2(pb[q][0].x, pb[q][0].y), pk_bf2(pb[q][0].z, pb[q][0].w),
                         pk_bf2(pb[q][1].x, pb[q][1].y), pk_bf2(pb[q][1].z, pb[q][1].w) };
            *(uint4*)&A_s[r * 32 + sw] = wa;
            *(uint4*)&B_s[r * 32 + sw] = wb;
        }
        __syncthreads();
        if (ks < 3) {   // prefetch next fp32 chunk; consumed after next barrier
            const int off = (ks + 1) * 64;
            #pragma unroll
            for (int q = 0; q < 2; ++q) {
                pa[q][0] = *(const float4*)(aptr[q] + off);
                pa[q][1] = *(const float4*)(aptr[q] + off + 4);
                pb[q][0] = *(const float4*)(bptr[q] + off);
                pb[q][1] = *(const float4*)(bptr[q] + off + 4);
            }
        }
        #pragma unroll
        for (int kk = 0; kk < 2; ++kk) {
            short8 af[4], bfj[2];
            #pragma unroll
            for (int i = 0; i < 4; ++i) {
                const int r  = wr * 64 + i * 16 + rl;
                const int sl = (kk * 4 + g4) ^ (r & 7);
                af[i] = *(const short8*)&A_s[r * 32 + sl * 4];
            }
            #pragma unroll
            for (int j = 0; j < 2; ++j) {
                const int r  = wc * 32 + j * 16 + rl;
                const int sl = (kk * 4 + g4) ^ (r & 7);
                bfj[j] = *(const short8*)&B_s[r * 32 + sl * 4];
            }
            #pragma unroll
            for (int i = 0; i < 4; ++i)
                #pragma unroll
                for (int j = 0; j < 2; ++j)
                    acc[i][j] = __builtin_amdgcn_mfma_f32_16x16x32_bf16(af[i], bfj[j], acc[i][j], 0, 0, 0);
        }
    }

    // fused epilogue: e = exp(1 + c/128); masked row/col sums; Dpos diagonal extraction
    float rs[4][4];
    float cs[2] = {0.f, 0.f};
    #pragma unroll
    for (int i = 0; i < 4; ++i)
        #pragma unroll
        for (int rg = 0; rg < 4; ++rg) rs[i][rg] = 0.f;

    #pragma unroll
    for (int i = 0; i < 4; ++i) {
        #pragma unroll
        for (int j = 0; j < 2; ++j) {
            const int kg = by * 128 + wc * 32 + j * 16 + rl;      // C/D: col = lane&15 [m89]
            #pragma unroll
            for (int rg = 0; rg < 4; ++rg) {
                const int pg = bx * 128 + wr * 64 + i * 16 + g4 * 4 + rg;  // row = (lane>>4)*4+reg
                const float c = acc[i][j][rg] * (1.f / 128.f);
                const float e = __expf(1.f + c);
                if (kg == pg) Dpos[pg] = c;                  // M[p,p]; fenced by grid.sync
                rs[i][rg] += (kg == 2 * pg + 1) ? 0.f : e;   // row-sum exclusion (mask_i)
                cs[j]     += (pg == 2 * kg)     ? 0.f : e;   // col-sum exclusion (mask_j)
            }
        }
    }

    // row reduction: over 16 cols (rl lanes), then across the 4 wc waves via LDS
    #pragma unroll
    for (int i = 0; i < 4; ++i) {
        #pragma unroll
        for (int rg = 0; rg < 4; ++rg) {
            float v = rs[i][rg];
            v += __shfl_xor(v, 1); v += __shfl_xor(v, 2);
            v += __shfl_xor(v, 4); v += __shfl_xor(v, 8);
            if (rl == 0) red[wc][wr * 64 + i * 16 + g4 * 4 + rg] = v;
        }
    }
    __syncthreads();
    if (t < 128)
        Srow[by * PN + bx * 128 + t] = red[0][t] + red[1][t] + red[2][t] + red[3][t];
    __syncthreads();   // before reusing red

    // col reduction: over 64 rows of the wave (g4 groups), then across wr waves
    #pragma unroll
    for (int j = 0; j < 2; ++j) {
        float v = cs[j];
        v += __shfl_xor(v, 16); v += __shfl_xor(v, 32);
        if (g4 == 0) red[wr][wc * 32 + j * 16 + rl] = v;
    }
    __syncthreads();
    if (t < 128)
        Scol[bx * PN + by * 128 + t] = red[0][t] + red[1][t];

    // ---- grid-wide barrier (release/acquire fence included) ----
    cg::this_grid().sync();

    // distributed finish: block b handles 8 pairs, one per wave
    const int b = by * 16 + bx;
    const int p = b * 8 + wid;
    float v32 = 0.f;
    if (lane < 16)       v32 = Srow[lane * PN + p];
    else if (lane < 32)  v32 = Scol[(lane - 16) * PN + p];
    v32 += __shfl_xor(v32, 1); v32 += __shfl_xor(v32, 2);
    v32 += __shfl_xor(v32, 4); v32 += __shfl_xor(v32, 8);
    v32 += __shfl_xor(v32, 16);
    if (lane == 0) {
        const float J = __logf(1e-8f + v32) - Dpos[p];
        const float m = fmaxf(J, 0.f);
        red[0][wid] = m * m;
    }
    __syncthreads();
    if (t == 0) {
        float ssum = 0.f;
        #pragma unroll
        for (int w = 0; w < 8; ++w) ssum += red[0][w];
        atomicAdd(out, ssum * (1.f / 4096.f));
    }
}

extern "C" void kernel_launch(void* const* d_in, const int* in_sizes, int n_in,
                              void* d_out, int out_size, void* d_ws, size_t ws_size,
                              hipStream_t stream) {
    const float* X = (const float*)d_in[0];
    float* ws   = (float*)d_ws;
    float* Srow = ws;                  // 16*2048
    float* Scol = Srow + 16 * PN;      // 16*2048
    float* Dpos = Scol + 16 * PN;      // 2048
    float* out  = (float*)d_out;

    void* args[] = { (void*)&X, (void*)&Srow, (void*)&Scol, (void*)&Dpos, (void*)&out };
    hipLaunchCooperativeKernel(reinterpret_cast<void*>(sml_coop),
                               dim3(16, 16), dim3(512), args, 0, stream);
}

// Round 10
// 16.349 us; speedup vs baseline: 3.2582x; 3.2582x over previous
//
#include <hip/hip_runtime.h>

#define PN 2048

typedef __attribute__((ext_vector_type(8))) short short8;
typedef __attribute__((ext_vector_type(4))) float f32x4;

static __device__ __forceinline__ unsigned int pk_bf2(float lo, float hi) {
    unsigned int ul = __float_as_uint(lo);
    unsigned int uh = __float_as_uint(hi);
    ul = (ul + 0x7fffu + ((ul >> 16) & 1u)) >> 16;   // RNE f32->bf16
    uh = (uh + 0x7fffu + ((uh >> 16) & 1u)) >> 16;
    return ul | (uh << 16);
}

// Single GEMM: M[p,k] = dot(X[2p], X[2k+1])/128, T = exp(1+M).
// neg[p] = rowsum_p(T)[excl k==2p+1] + colsum_p(T)[excl row==2p];
// J[p] = log(1e-8+neg[p]) - M[p,p]; out = mean(max(J,0)^2).
// Full-K-in-LDS GEMM: 128x128 tile, K=256 in 2 chunks of 128 (double-buffered),
// only 2 barriers in the whole main body. Grid (16,16)=256 blocks (1/CU), 512 thr.
// ws: Srow[16][2048], Scol[16][2048], Dpos[2048] (each written once, read by finish).

__global__ __launch_bounds__(512, 2) void sml_mfma(
    const float* __restrict__ X, float* __restrict__ Srow, float* __restrict__ Scol,
    float* __restrict__ Dpos, float* __restrict__ out)
{
    // bf16[buf][128 rows][128 cols] = 8192 uints per buf per matrix; 128 KB total
    __shared__ __align__(16) unsigned int A_s[2 * 128 * 64];
    __shared__ __align__(16) unsigned int B_s[2 * 128 * 64];
    __shared__ float red[4][128];

    const int bx = blockIdx.x, by = blockIdx.y;
    const int t = threadIdx.x;                 // 0..511, 8 waves
    const int lane = t & 63, wid = t >> 6;
    const int wr = wid >> 2, wc = wid & 3;     // wave grid 2x4 over (64-row x 32-col) subtiles
    const int g4 = lane >> 4, rl = lane & 15;

    if (bx == 0 && by == 0 && t == 0) out[0] = 0.f;   // finish kernel accumulates atomically

    // staging: thread owns 16B slot s (8 bf16) of rows r0+32q (q<4); chunk = 128 cols
    const int s  = t & 15;
    const int r0 = t >> 4;

    const float* aP[4];
    const float* bP[4];
    #pragma unroll
    for (int q = 0; q < 4; ++q) {
        const int r = r0 + 32 * q;
        aP[q] = X + (size_t)(2 * (bx * 128 + r)) * 256 + s * 8;
        bP[q] = X + (size_t)(2 * (by * 128 + r) + 1) * 256 + s * 8;
    }

    f32x4 acc[4][2];
    #pragma unroll
    for (int i = 0; i < 4; ++i)
        #pragma unroll
        for (int j = 0; j < 2; ++j) acc[i][j] = (f32x4){0.f, 0.f, 0.f, 0.f};

    // ---- issue chunk-0 loads (16 float4 in flight) ----
    float4 a0[4][2], b0[4][2];
    #pragma unroll
    for (int q = 0; q < 4; ++q) {
        a0[q][0] = *(const float4*)(aP[q]);     a0[q][1] = *(const float4*)(aP[q] + 4);
        b0[q][0] = *(const float4*)(bP[q]);     b0[q][1] = *(const float4*)(bP[q] + 4);
    }
    // ---- convert + write buf0 ----
    #pragma unroll
    for (int q = 0; q < 4; ++q) {
        const int r  = r0 + 32 * q;
        const int sw = (s ^ (r & 15)) << 2;
        uint4 wa = { pk_bf2(a0[q][0].x, a0[q][0].y), pk_bf2(a0[q][0].z, a0[q][0].w),
                     pk_bf2(a0[q][1].x, a0[q][1].y), pk_bf2(a0[q][1].z, a0[q][1].w) };
        uint4 wb = { pk_bf2(b0[q][0].x, b0[q][0].y), pk_bf2(b0[q][0].z, b0[q][0].w),
                     pk_bf2(b0[q][1].x, b0[q][1].y), pk_bf2(b0[q][1].z, b0[q][1].w) };
        *(uint4*)&A_s[r * 64 + sw] = wa;
        *(uint4*)&B_s[r * 64 + sw] = wb;
    }
    __syncthreads();   // barrier 1: buf0 ready

    // ---- issue chunk-1 loads; latency hides under buf0 compute ----
    float4 a1[4][2], b1[4][2];
    #pragma unroll
    for (int q = 0; q < 4; ++q) {
        a1[q][0] = *(const float4*)(aP[q] + 128); a1[q][1] = *(const float4*)(aP[q] + 132);
        b1[q][0] = *(const float4*)(bP[q] + 128); b1[q][1] = *(const float4*)(bP[q] + 132);
    }

    // ---- compute buf0 ----
    #pragma unroll
    for (int kk = 0; kk < 4; ++kk) {
        short8 af[4], bfj[2];
        #pragma unroll
        for (int i = 0; i < 4; ++i) {
            const int r  = wr * 64 + i * 16 + rl;
            const int sl = ((kk << 2) + g4) ^ (r & 15);
            af[i] = *(const short8*)&A_s[r * 64 + sl * 4];
        }
        #pragma unroll
        for (int j = 0; j < 2; ++j) {
            const int r  = wc * 32 + j * 16 + rl;
            const int sl = ((kk << 2) + g4) ^ (r & 15);
            bfj[j] = *(const short8*)&B_s[r * 64 + sl * 4];
        }
        #pragma unroll
        for (int i = 0; i < 4; ++i)
            #pragma unroll
            for (int j = 0; j < 2; ++j)
                acc[i][j] = __builtin_amdgcn_mfma_f32_16x16x32_bf16(af[i], bfj[j], acc[i][j], 0, 0, 0);
    }

    // ---- convert + write buf1 (no barrier needed before: distinct addresses) ----
    #pragma unroll
    for (int q = 0; q < 4; ++q) {
        const int r  = r0 + 32 * q;
        const int sw = (s ^ (r & 15)) << 2;
        uint4 wa = { pk_bf2(a1[q][0].x, a1[q][0].y), pk_bf2(a1[q][0].z, a1[q][0].w),
                     pk_bf2(a1[q][1].x, a1[q][1].y), pk_bf2(a1[q][1].z, a1[q][1].w) };
        uint4 wb = { pk_bf2(b1[q][0].x, b1[q][0].y), pk_bf2(b1[q][0].z, b1[q][0].w),
                     pk_bf2(b1[q][1].x, b1[q][1].y), pk_bf2(b1[q][1].z, b1[q][1].w) };
        *(uint4*)&A_s[8192 + r * 64 + sw] = wa;
        *(uint4*)&B_s[8192 + r * 64 + sw] = wb;
    }
    __syncthreads();   // barrier 2: buf1 ready

    // ---- compute buf1 ----
    #pragma unroll
    for (int kk = 0; kk < 4; ++kk) {
        short8 af[4], bfj[2];
        #pragma unroll
        for (int i = 0; i < 4; ++i) {
            const int r  = wr * 64 + i * 16 + rl;
            const int sl = ((kk << 2) + g4) ^ (r & 15);
            af[i] = *(const short8*)&A_s[8192 + r * 64 + sl * 4];
        }
        #pragma unroll
        for (int j = 0; j < 2; ++j) {
            const int r  = wc * 32 + j * 16 + rl;
            const int sl = ((kk << 2) + g4) ^ (r & 15);
            bfj[j] = *(const short8*)&B_s[8192 + r * 64 + sl * 4];
        }
        #pragma unroll
        for (int i = 0; i < 4; ++i)
            #pragma unroll
            for (int j = 0; j < 2; ++j)
                acc[i][j] = __builtin_amdgcn_mfma_f32_16x16x32_bf16(af[i], bfj[j], acc[i][j], 0, 0, 0);
    }

    // fused epilogue: e = exp(1 + c/128); masked row/col sums; Dpos diagonal extraction
    float rs[4][4];
    float cs[2] = {0.f, 0.f};
    #pragma unroll
    for (int i = 0; i < 4; ++i)
        #pragma unroll
        for (int rg = 0; rg < 4; ++rg) rs[i][rg] = 0.f;

    #pragma unroll
    for (int i = 0; i < 4; ++i) {
        #pragma unroll
        for (int j = 0; j < 2; ++j) {
            const int kg = by * 128 + wc * 32 + j * 16 + rl;      // C/D: col = lane&15 [m89]
            #pragma unroll
            for (int rg = 0; rg < 4; ++rg) {
                const int pg = bx * 128 + wr * 64 + i * 16 + g4 * 4 + rg;  // row = (lane>>4)*4+reg
                const float c = acc[i][j][rg] * (1.f / 128.f);
                const float e = __expf(1.f + c);
                if (kg == pg) Dpos[pg] = c;                  // M[p,p]
                rs[i][rg] += (kg == 2 * pg + 1) ? 0.f : e;   // row-sum exclusion (mask_i)
                cs[j]     += (pg == 2 * kg)     ? 0.f : e;   // col-sum exclusion (mask_j)
            }
        }
    }

    // row reduction: over 16 cols (rl lanes), then across the 4 wc waves via LDS
    #pragma unroll
    for (int i = 0; i < 4; ++i) {
        #pragma unroll
        for (int rg = 0; rg < 4; ++rg) {
            float v = rs[i][rg];
            v += __shfl_xor(v, 1); v += __shfl_xor(v, 2);
            v += __shfl_xor(v, 4); v += __shfl_xor(v, 8);
            if (rl == 0) red[wc][wr * 64 + i * 16 + g4 * 4 + rg] = v;
        }
    }
    __syncthreads();
    if (t < 128)
        Srow[by * PN + bx * 128 + t] = red[0][t] + red[1][t] + red[2][t] + red[3][t];
    __syncthreads();   // before reusing red

    // col reduction: over 64 rows of the wave (g4 groups), then across wr waves
    #pragma unroll
    for (int j = 0; j < 2; ++j) {
        float v = cs[j];
        v += __shfl_xor(v, 16); v += __shfl_xor(v, 32);
        if (g4 == 0) red[wr][wc * 32 + j * 16 + rl] = v;
    }
    __syncthreads();
    if (t < 128)
        Scol[bx * PN + by * 128 + t] = red[0][t] + red[1][t];
}

__global__ __launch_bounds__(64) void sml_finish(
    const float* __restrict__ Srow, const float* __restrict__ Scol,
    const float* __restrict__ Dpos, float* __restrict__ out)
{
    const int t = threadIdx.x;
    const int p = blockIdx.x * 64 + t;
    float ssum = 0.f;
    #pragma unroll
    for (int g = 0; g < 16; ++g) ssum += Srow[g * PN + p];
    #pragma unroll
    for (int g = 0; g < 16; ++g) ssum += Scol[g * PN + p];
    const float J = __logf(1e-8f + ssum) - Dpos[p];
    const float v = fmaxf(J, 0.f);
    float local = v * v;
    #pragma unroll
    for (int m = 1; m < 64; m <<= 1) local += __shfl_xor(local, m);
    if (t == 0) atomicAdd(out, local * (1.f / 4096.f));
}

extern "C" void kernel_launch(void* const* d_in, const int* in_sizes, int n_in,
                              void* d_out, int out_size, void* d_ws, size_t ws_size,
                              hipStream_t stream) {
    const float* X = (const float*)d_in[0];
    float* ws   = (float*)d_ws;
    float* Srow = ws;                  // 16*2048
    float* Scol = Srow + 16 * PN;      // 16*2048
    float* Dpos = Scol + 16 * PN;      // 2048
    float* out  = (float*)d_out;

    sml_mfma<<<dim3(16, 16), dim3(512), 0, stream>>>(X, Srow, Scol, Dpos, out);
    sml_finish<<<32, dim3(64), 0, stream>>>(Srow, Scol, Dpos, out);
}